// Round 1
// baseline (502.848 us; speedup 1.0000x reference)
//
#include <hip/hip_runtime.h>
#include <hip/hip_bf16.h>
#include <stdint.h>

typedef __attribute__((ext_vector_type(8))) short short8;
typedef __attribute__((ext_vector_type(4))) short short4_t;
typedef __attribute__((ext_vector_type(4))) float f32x4;

#define DEVFN static __device__ __forceinline__

constexpr int BATCH = 16;
constexpr int GRAPH = 1024;
constexpr int IDIM  = 512;
constexpr int EDIM  = 512;
constexpr int NH    = 8;
constexpr int KD    = 64;
constexpr int TOK   = BATCH * GRAPH;   // 16384
constexpr int QKC   = 1024;            // proj row width (Q|K)
constexpr int HC    = 1024;            // heads row width (8 heads * 128)
constexpr float SMSCALE = 0.125f * 1.44269504088896340736f; // 1/sqrt(64) * log2(e)

DEVFN unsigned short f2bf(float x) {
    union { float f; unsigned u; } v; v.f = x;
    unsigned r = v.u + 0x7fffu + ((v.u >> 16) & 1u);
    return (unsigned short)(r >> 16);
}

DEVFN void load16(const void* g, void* l) {
    __builtin_amdgcn_global_load_lds(
        (const __attribute__((address_space(1))) void*)g,
        (__attribute__((address_space(3))) void*)l, 16, 0, 0);
}

// ---------------- input conversion: fp32 -> bf16 ----------------
__global__ __launch_bounds__(256) void cvt_x_kernel(const float4* __restrict__ x,
                                                    short4_t* __restrict__ y) {
    const int i = blockIdx.x * 256 + threadIdx.x;
    const float4 v = x[i];
    short4_t o;
    o[0] = (short)f2bf(v.x); o[1] = (short)f2bf(v.y);
    o[2] = (short)f2bf(v.z); o[3] = (short)f2bf(v.w);
    y[i] = o;
}

// pack W_query|W_key|W_val (one stream) -> Bt layout [2048][512] bf16
__global__ __launch_bounds__(256) void pack_qkv_kernel(const float* __restrict__ Wq,
                                                       const float* __restrict__ Wk,
                                                       const float* __restrict__ Wv,
                                                       unsigned short* __restrict__ Wp) {
    const int idx = blockIdx.x * 256 + threadIdx.x;  // col*512 + d
    const int col = idx >> 9, d = idx & 511;
    float v;
    if (col < 512)       v = Wq[((col >> 6) * IDIM + d) * KD + (col & 63)];
    else if (col < 1024) v = Wk[(((col - 512) >> 6) * IDIM + d) * KD + (col & 63)];
    else                 v = Wv[(((col - 1024) >> 6) * IDIM + d) * KD + (col & 63)];
    Wp[idx] = f2bf(v);
}

// pack W_out [8][128][512] -> Bt [512][1024] bf16 ; flat src index = c*512 + e
__global__ __launch_bounds__(256) void pack_out_kernel(const float* __restrict__ W,
                                                       unsigned short* __restrict__ Wp) {
    const int idx = blockIdx.x * 256 + threadIdx.x;  // e*1024 + c
    const int e = idx >> 10, c = idx & 1023;
    Wp[idx] = f2bf(W[(size_t)c * EDIM + e]);
}

// ---------------- GEMM: C[M][N] = A[M][K] * Bt[N][K]^T (bf16 MFMA, f32 acc) --
// VSPLIT: n0 >= 1024 blocks write bf16 TRANSPOSED into Vt[n-1024][m] (V proj).
template<int K, bool VSPLIT, typename OutT>
__global__ __launch_bounds__(256)
void gemm_bt_kernel(const unsigned short* __restrict__ A0, const unsigned short* __restrict__ A1,
                    const unsigned short* __restrict__ B0, const unsigned short* __restrict__ B1,
                    OutT* __restrict__ C0, OutT* __restrict__ C1,
                    unsigned short* __restrict__ V0, unsigned short* __restrict__ V1,
                    int ldc)
{
    __shared__ unsigned short As[128 * 64];
    __shared__ unsigned short Bs[128 * 64];
    const unsigned short* A  = blockIdx.z ? A1 : A0;
    const unsigned short* Bt = blockIdx.z ? B1 : B0;

    const int tid = threadIdx.x, wave = tid >> 6, lane = tid & 63;
    const int g = lane >> 4, ln = lane & 15;
    const int m0 = blockIdx.x * 128, n0 = blockIdx.y * 128;
    const int wr = (wave >> 1) * 64, wc = (wave & 1) * 64;

    f32x4 acc[4][4] = {};

    for (int k0 = 0; k0 < K; k0 += 64) {
        // stage 128x64 A and Bt tiles; linear LDS dest, inverse-swizzled global src
        #pragma unroll
        for (int j = 0; j < 4; ++j) {
            const int c = (wave * 4 + j) * 64 + lane;      // 0..1023 chunks of 16B
            const int row = c >> 3;
            const int col = ((c & 7) ^ (row & 7)) * 8;
            load16(A  + (size_t)(m0 + row) * K + k0 + col, (char*)As + c * 16);
            load16(Bt + (size_t)(n0 + row) * K + k0 + col, (char*)Bs + c * 16);
        }
        __syncthreads();
        #pragma unroll
        for (int kk = 0; kk < 2; ++kk) {
            short8 af[4], bfr[4];
            #pragma unroll
            for (int i = 0; i < 4; ++i) {
                const int ra = wr + i * 16 + ln;
                af[i]  = *(const short8*)((const char*)As + ra * 128 + (((kk * 4 + g) ^ (ra & 7)) * 16));
                const int rb = wc + i * 16 + ln;
                bfr[i] = *(const short8*)((const char*)Bs + rb * 128 + (((kk * 4 + g) ^ (rb & 7)) * 16));
            }
            #pragma unroll
            for (int mi = 0; mi < 4; ++mi)
                #pragma unroll
                for (int ni = 0; ni < 4; ++ni)
                    acc[mi][ni] = __builtin_amdgcn_mfma_f32_16x16x32_bf16(af[mi], bfr[ni], acc[mi][ni], 0, 0, 0);
        }
        __syncthreads();
    }

    if (!VSPLIT || n0 < 1024) {
        OutT* C = blockIdx.z ? C1 : C0;
        #pragma unroll
        for (int mi = 0; mi < 4; ++mi)
            #pragma unroll
            for (int ni = 0; ni < 4; ++ni)
                #pragma unroll
                for (int r = 0; r < 4; ++r) {
                    const size_t m = (size_t)(m0 + wr + mi * 16 + g * 4 + r);
                    const size_t n = (size_t)(n0 + wc + ni * 16 + ln);
                    if constexpr (sizeof(OutT) == 4) C[m * ldc + n] = acc[mi][ni][r];
                    else                             C[m * ldc + n] = (OutT)f2bf(acc[mi][ni][r]);
                }
    } else {
        unsigned short* Vt = blockIdx.z ? V1 : V0;
        #pragma unroll
        for (int mi = 0; mi < 4; ++mi)
            #pragma unroll
            for (int ni = 0; ni < 4; ++ni) {
                short4_t pk;
                pk[0] = (short)f2bf(acc[mi][ni][0]);
                pk[1] = (short)f2bf(acc[mi][ni][1]);
                pk[2] = (short)f2bf(acc[mi][ni][2]);
                pk[3] = (short)f2bf(acc[mi][ni][3]);
                const size_t vrow = (size_t)(n0 - 1024 + wc + ni * 16 + ln);
                const size_t mcol = (size_t)(m0 + wr + mi * 16 + g * 4);
                *(short4_t*)(Vt + vrow * TOK + mcol) = pk;
            }
    }
}

// ---------------- fused flash attention (dual-V, swapped QK^T / swapped PV) --
// grid: (qt=16, a*8+h=16, b=16), 4 waves/block, 16 q-rows per wave.
__global__ __launch_bounds__(256)
void attn_kernel(const unsigned short* __restrict__ projn,
                 const unsigned short* __restrict__ projp,
                 const unsigned short* __restrict__ Vtn,
                 const unsigned short* __restrict__ Vtp,
                 unsigned short* __restrict__ headsn,
                 unsigned short* __restrict__ headsp)
{
    __shared__ unsigned short Kl[64 * 64];    //  8KB  [key][d]
    __shared__ unsigned short Vl[128 * 64];   // 16KB  [v (0-63 node,64-127 pos)][key]
    __shared__ unsigned short Pl[4 * 16 * 64];//  8KB  per-wave [q][key]

    const int qt = blockIdx.x;
    const int a  = blockIdx.y >> 3, h = blockIdx.y & 7;
    const int b  = blockIdx.z;
    const int tid = threadIdx.x, wave = tid >> 6, lane = tid & 63;
    const int g = lane >> 4, ln = lane & 15;

    const unsigned short* proj = a ? projp : projn;
    const int tok0 = b * GRAPH;
    const size_t qrow = (size_t)(tok0 + qt * 64 + wave * 16 + ln); // this lane's q token
    const int qc  = h * KD;
    const int kc  = IDIM + h * KD;
    const int vr0 = (a * NH + h) * KD;

    // Q fragments (B-operand of swapped QK^T): q = ln, d = d0*32 + g*8 + e
    const short8 qf0 = *(const short8*)(proj + qrow * QKC + qc + g * 8);
    const short8 qf1 = *(const short8*)(proj + qrow * QKC + qc + 32 + g * 8);

    f32x4 oacc[8] = {};              // O^T frags: col = q = ln, rows = v
    float m_run = -INFINITY, l_run = 0.f;

    for (int kt = 0; kt < 16; ++kt) {
        const int key0 = kt * 64;
        #pragma unroll
        for (int j = 0; j < 2; ++j) {  // stage K tile (512 chunks)
            const int c = (wave * 2 + j) * 64 + lane;
            const int row = c >> 3;
            const int col = ((c & 7) ^ (row & 7)) * 8;
            load16(proj + (size_t)(tok0 + key0 + row) * QKC + kc + col, (char*)Kl + c * 16);
        }
        #pragma unroll
        for (int j = 0; j < 4; ++j) {  // stage Vt tile (1024 chunks)
            const int c = (wave * 4 + j) * 64 + lane;
            const int row = c >> 3;
            const int col = ((c & 7) ^ (row & 7)) * 8;
            const unsigned short* base = (row < 64)
                ? (Vtn + (size_t)(vr0 + row) * TOK)
                : (Vtp + (size_t)(vr0 + row - 64) * TOK);
            load16(base + tok0 + key0 + col, (char*)Vl + c * 16);
        }
        __syncthreads();

        // S^T = K * Q^T : lane holds S[q=ln][key = rb*16 + g*4 + r]
        f32x4 sacc[4] = {};
        #pragma unroll
        for (int rb = 0; rb < 4; ++rb) {
            const int row = rb * 16 + ln;
            const short8 kf0 = *(const short8*)((const char*)Kl + row * 128 + ((g ^ (row & 7)) * 16));
            const short8 kf1 = *(const short8*)((const char*)Kl + row * 128 + (((4 + g) ^ (row & 7)) * 16));
            sacc[rb] = __builtin_amdgcn_mfma_f32_16x16x32_bf16(kf0, qf0, sacc[rb], 0, 0, 0);
            sacc[rb] = __builtin_amdgcn_mfma_f32_16x16x32_bf16(kf1, qf1, sacc[rb], 0, 0, 0);
        }

        // online softmax, q = ln domain (4 g-lanes replicate the row state)
        float p[16];
        float tmax = -INFINITY;
        #pragma unroll
        for (int rb = 0; rb < 4; ++rb)
            #pragma unroll
            for (int r = 0; r < 4; ++r) {
                const float v = sacc[rb][r] * SMSCALE;
                p[rb * 4 + r] = v;
                tmax = fmaxf(tmax, v);
            }
        tmax = fmaxf(tmax, __shfl_xor(tmax, 16));
        tmax = fmaxf(tmax, __shfl_xor(tmax, 32));
        const float m_new = fmaxf(m_run, tmax);
        const float alpha = __builtin_amdgcn_exp2f(m_run - m_new);
        float psum = 0.f;
        #pragma unroll
        for (int i = 0; i < 16; ++i) { p[i] = __builtin_amdgcn_exp2f(p[i] - m_new); psum += p[i]; }
        psum += __shfl_xor(psum, 16);
        psum += __shfl_xor(psum, 32);
        l_run = l_run * alpha + psum;
        m_run = m_new;
        #pragma unroll
        for (int vb = 0; vb < 8; ++vb) {
            oacc[vb][0] *= alpha; oacc[vb][1] *= alpha;
            oacc[vb][2] *= alpha; oacc[vb][3] *= alpha;
        }

        // P -> LDS (wave-private), bf16, swizzled; keys rb*16+g*4..+3 at row q=ln
        const int pbase = wave * 2048 + ln * 128;
        #pragma unroll
        for (int rb = 0; rb < 4; ++rb) {
            short4_t pk;
            pk[0] = (short)f2bf(p[rb * 4 + 0]);
            pk[1] = (short)f2bf(p[rb * 4 + 1]);
            pk[2] = (short)f2bf(p[rb * 4 + 2]);
            pk[3] = (short)f2bf(p[rb * 4 + 3]);
            const int byte = pbase + ((rb * 32 + g * 8) ^ ((ln & 7) * 16));
            *(short4_t*)((char*)Pl + byte) = pk;
        }
        const short8 pf0 = *(const short8*)((const char*)Pl + pbase + ((g ^ (ln & 7)) * 16));
        const short8 pf1 = *(const short8*)((const char*)Pl + pbase + (((4 + g) ^ (ln & 7)) * 16));

        // O^T += V^T * P^T
        #pragma unroll
        for (int vb = 0; vb < 8; ++vb) {
            const int row = vb * 16 + ln;
            const short8 vf0 = *(const short8*)((const char*)Vl + row * 128 + ((g ^ (row & 7)) * 16));
            const short8 vf1 = *(const short8*)((const char*)Vl + row * 128 + (((4 + g) ^ (row & 7)) * 16));
            oacc[vb] = __builtin_amdgcn_mfma_f32_16x16x32_bf16(vf0, pf0, oacc[vb], 0, 0, 0);
            oacc[vb] = __builtin_amdgcn_mfma_f32_16x16x32_bf16(vf1, pf1, oacc[vb], 0, 0, 0);
        }
        __syncthreads();
    }

    const float inv = 1.0f / l_run;
    #pragma unroll
    for (int vb = 0; vb < 8; ++vb) {
        short4_t pk;
        pk[0] = (short)f2bf(oacc[vb][0] * inv);
        pk[1] = (short)f2bf(oacc[vb][1] * inv);
        pk[2] = (short)f2bf(oacc[vb][2] * inv);
        pk[3] = (short)f2bf(oacc[vb][3] * inv);
        unsigned short* heads = (vb < 4) ? headsn : headsp;
        const int col = h * 128 + a * 64 + (vb & 3) * 16 + g * 4;
        *(short4_t*)(heads + qrow * HC + col) = pk;
    }
}

// ---------------- host launch ----------------
extern "C" void kernel_launch(void* const* d_in, const int* in_sizes, int n_in,
                              void* d_out, int out_size, void* d_ws, size_t ws_size,
                              hipStream_t stream)
{
    const float* hn  = (const float*)d_in[0];
    const float* hp  = (const float*)d_in[1];
    const float* Wqn = (const float*)d_in[2];
    const float* Wqp = (const float*)d_in[3];
    const float* Wkn = (const float*)d_in[4];
    const float* Wkp = (const float*)d_in[5];
    const float* Wvn = (const float*)d_in[6];
    const float* Wvp = (const float*)d_in[7];
    const float* Won = (const float*)d_in[8];
    const float* Wop = (const float*)d_in[9];
    float* out = (float*)d_out;

    char* ws = (char*)d_ws;
    size_t off = 0;
    auto take = [&](size_t nbytes) -> char* {
        char* p = ws + off;
        off += (nbytes + 255) & ~(size_t)255;
        return p;
    };
    unsigned short* Xn  = (unsigned short*)take((size_t)TOK * IDIM * 2);
    unsigned short* Xp  = (unsigned short*)take((size_t)TOK * IDIM * 2);
    unsigned short* Wn  = (unsigned short*)take((size_t)2048 * 512 * 2);
    unsigned short* Wp  = (unsigned short*)take((size_t)2048 * 512 * 2);
    unsigned short* WoN = (unsigned short*)take((size_t)512 * 1024 * 2);
    unsigned short* WoP = (unsigned short*)take((size_t)512 * 1024 * 2);
    unsigned short* Pn  = (unsigned short*)take((size_t)TOK * QKC * 2);
    unsigned short* Pp  = (unsigned short*)take((size_t)TOK * QKC * 2);
    unsigned short* Vtn = (unsigned short*)take((size_t)1024 * TOK * 2);
    unsigned short* Vtp = (unsigned short*)take((size_t)1024 * TOK * 2);
    unsigned short* Hn  = (unsigned short*)take((size_t)TOK * HC * 2);
    unsigned short* Hp  = (unsigned short*)take((size_t)TOK * HC * 2);

    cvt_x_kernel<<<TOK * IDIM / 4 / 256, 256, 0, stream>>>((const float4*)hn, (short4_t*)Xn);
    cvt_x_kernel<<<TOK * IDIM / 4 / 256, 256, 0, stream>>>((const float4*)hp, (short4_t*)Xp);
    pack_qkv_kernel<<<2048 * 512 / 256, 256, 0, stream>>>(Wqn, Wkn, Wvn, Wn);
    pack_qkv_kernel<<<2048 * 512 / 256, 256, 0, stream>>>(Wqp, Wkp, Wvp, Wp);
    pack_out_kernel<<<512 * 1024 / 256, 256, 0, stream>>>(Won, WoN);
    pack_out_kernel<<<512 * 1024 / 256, 256, 0, stream>>>(Wop, WoP);

    // projections: [16384,512] x [512,2048] per stream; V columns stored transposed
    gemm_bt_kernel<512, true, unsigned short><<<dim3(128, 16, 2), 256, 0, stream>>>(
        Xn, Xp, Wn, Wp, Pn, Pp, Vtn, Vtp, QKC);

    attn_kernel<<<dim3(16, 16, 16), 256, 0, stream>>>(Pn, Pp, Vtn, Vtp, Hn, Hp);

    // output: [16384,1024] x [1024,512] per stream -> fp32 d_out (node then pos)
    gemm_bt_kernel<1024, false, float><<<dim3(128, 4, 2), 256, 0, stream>>>(
        Hn, Hp, WoN, WoP, out, out + (size_t)TOK * EDIM,
        (unsigned short*)nullptr, (unsigned short*)nullptr, EDIM);
}